// Round 3
// baseline (149444.470 us; speedup 1.0000x reference)
//
#include <hip/hip_runtime.h>
#include <hip/hip_cooperative_groups.h>

namespace cg = cooperative_groups;

constexpr int NT = 512;   // timesteps
constexpr int NB = 64;    // batch
constexpr int NH = 1024;  // hidden
constexpr int NI = 1024;  // input
constexpr long long BH  = (long long)NB * NH;   // 65536
constexpr long long TBH = (long long)NT * BH;

__device__ __forceinline__ float sigm(float z) { return 1.0f / (1.0f + __expf(-z)); }

// grid = 512 blocks (2/CU, cooperative), block = 256 threads, 2 waves/SIMD.
// Lane pair (tid even/odd) shares one (b,j) output: even lane accumulates
// gate rows {i,f}, odd lane {g,o} — each thread 2 dot-products of K=2048.
// Pair combine via __shfl_xor(.,1); cell state c + skip ring live on even lane.
// blockIdx = bg*128 + jg keeps blockIdx%8 == jg%8: the 4 bg-blocks of a jg
// land on one XCD, whose ~4 MB w_ih/w_hh slice stays L2-resident for all 512 steps.
__global__ __launch_bounds__(256, 2)
void skiplstm(const float* __restrict__ x,
              const float* __restrict__ h0,
              const float* __restrict__ c0,
              const float* __restrict__ w_ih,
              const float* __restrict__ w_hh,
              const float* __restrict__ b_ih,
              const float* __restrict__ b_hh,
              const int* __restrict__ bias_flag,
              float* __restrict__ out)   // [T][B][H] then h_final, c_final
{
    cg::grid_group grid = cg::this_grid();

    const int tid = threadIdx.x;
    const int gp  = tid & 1;              // 0: gates {i,f}; 1: gates {g,o}
    const int pr  = tid >> 1;             // pair id 0..127
    const int bg  = blockIdx.x >> 7;      // 0..3
    const int jg  = blockIdx.x & 127;     // 0..127
    const int b   = bg * 16 + (pr >> 3);  // 0..63
    const int j   = jg * 8  + (pr & 7);   // 0..1023
    const int gA  = gp * 2;               // gate row A (0=i or 2=g)
    const int gB  = gp * 2 + 1;           // gate row B (1=f or 3=o)

    const float4* wiA = (const float4*)(w_ih + (size_t)(gA * NH + j) * NI);
    const float4* wiB = (const float4*)(w_ih + (size_t)(gB * NH + j) * NI);
    const float4* whA = (const float4*)(w_hh + (size_t)(gA * NH + j) * NH);
    const float4* whB = (const float4*)(w_hh + (size_t)(gB * NH + j) * NH);

    const float bsc = (bias_flag[0] != 0) ? 1.0f : 0.0f;
    const float bA = (b_ih[gA * NH + j] + b_hh[gA * NH + j]) * bsc;
    const float bB = (b_ih[gB * NH + j] + b_hh[gB * NH + j]) * bsc;

    float c = c0[(size_t)b * NH + j];     // meaningful on even lanes
    // 4-deep register ring of this pair's post-skip h (valid on even lanes).
    // Static shift each step -> stays in registers (no runtime indexing).
    float q0 = 0.f, q1 = 0.f, q2 = 0.f, q3 = 0.f;

    for (int t = 0; t < NT; ++t) {
        float aA = bA, aB = bB;

        // ---- x_t @ w_ih^T (independent of recurrence; runs pre-barrier) ----
        const float4* xr = (const float4*)(x + ((size_t)t * NB + b) * NI);
        #pragma unroll 4
        for (int k = 0; k < NI / 4; ++k) {
            float4 v = xr[k], wa = wiA[k], wb = wiB[k];
            aA += v.x * wa.x + v.y * wa.y + v.z * wa.z + v.w * wa.w;
            aB += v.x * wb.x + v.y * wb.y + v.z * wb.z + v.w * wb.w;
        }

        // Make every block's out[t-1] writes visible before the h-GEMM.
        grid.sync();

        // ---- h_{t-1} @ w_hh^T ; h_{t-1} lives in out[t-1] (post-skip h) ----
        const float* hbase = (t == 0) ? h0 : (out + (size_t)(t - 1) * BH);
        const float4* hr = (const float4*)(hbase + (size_t)b * NH);
        #pragma unroll 4
        for (int k = 0; k < NH / 4; ++k) {
            float4 v = hr[k], wa = whA[k], wb = whB[k];
            aA += v.x * wa.x + v.y * wa.y + v.z * wa.z + v.w * wa.w;
            aB += v.x * wb.x + v.y * wb.y + v.z * wb.z + v.w * wb.w;
        }

        // ---- pair exchange: even lane gets (g, o) partials from odd lane ----
        float pG = __shfl_xor(aA, 1);     // on even lanes: g-gate pre-activation
        float pO = __shfl_xor(aB, 1);     // on even lanes: o-gate pre-activation

        // Gate math meaningful on even lanes; odd lanes compute bounded garbage
        // (all through sigm/tanh, no NaN source) and never write.
        float ig = sigm(aA);
        float fg = sigm(aB);
        float gv = tanhf(pG);
        float og = sigm(pO);
        c = fg * c + ig * gv;
        float hn = og * tanhf(c);
        float ho = hn + ((t >= 4) ? q3 : 0.0f);   // skip: own out[t-4]
        q3 = q2; q2 = q1; q1 = q0; q0 = ho;
        if (gp == 0)
            out[(size_t)t * BH + (size_t)b * NH + j] = ho;
    }

    // Tuple tail: h_final = out[T-1], c_final.
    if (gp == 0) {
        out[TBH + (size_t)b * NH + j] = q0;
        out[TBH + BH + (size_t)b * NH + j] = c;
    }
}

extern "C" void kernel_launch(void* const* d_in, const int* in_sizes, int n_in,
                              void* d_out, int out_size, void* d_ws, size_t ws_size,
                              hipStream_t stream) {
    const float* x    = (const float*)d_in[0];
    const float* h0   = (const float*)d_in[1];
    const float* c0   = (const float*)d_in[2];
    const float* w_ih = (const float*)d_in[3];
    const float* w_hh = (const float*)d_in[4];
    const float* b_ih = (const float*)d_in[5];
    const float* b_hh = (const float*)d_in[6];
    const int* bias   = (const int*)d_in[7];
    float* out        = (float*)d_out;

    void* args[] = {(void*)&x, (void*)&h0, (void*)&c0, (void*)&w_ih, (void*)&w_hh,
                    (void*)&b_ih, (void*)&b_hh, (void*)&bias, (void*)&out};
    hipLaunchCooperativeKernel((void*)skiplstm, dim3(512), dim3(256), args, 0, stream);
}

// Round 5
// 29224.826 us; speedup vs baseline: 5.1136x; 5.1136x over previous
//
#include <hip/hip_runtime.h>
#include <hip/hip_cooperative_groups.h>

namespace cg = cooperative_groups;

constexpr int NT = 512;   // timesteps
constexpr int NB = 64;    // batch
constexpr int NH = 1024;  // hidden
constexpr int NI = 1024;  // input (== NH, row stride 1024 for x and h)
constexpr long long BH  = (long long)NB * NH;
constexpr long long TBH = (long long)NT * BH;

constexpr int JPB  = 4;            // j columns per block
constexpr int NBLK = NH / JPB;     // 256 blocks = 1/CU (cooperative-resident)
constexpr int NTHR = 512;          // 8 waves
constexpr int CK   = 64;           // k-chunk staged in LDS
constexpr int NCH  = NI / CK;      // 16 chunks per matrix
constexpr int WSTR = 1028;         // w row stride (floats): rows 4 banks apart (2-way max = free)
constexpr int ASTR = 68;           // act row stride (floats): b rows 4 banks apart (conflict-free)
constexpr int W_FLOATS = 32 * WSTR;            // 32 weight rows resident
constexpr size_t LDS_BYTES = (size_t)(W_FLOATS + 64 * ASTR) * 4;  // 148,992 B

__device__ __forceinline__ float sigm(float z) { return 1.0f / (1.0f + __expf(-z)); }
__device__ __forceinline__ float dot4(float4 a, float4 b) {
    return a.x * b.x + a.y * b.y + a.z * b.z + a.w * b.w;
}

// 256 blocks x 512 threads, persistent. Block owns j = blockIdx*4 .. +3, all 64 b.
// LDS: 32 weight rows [row = j4*4 + gate (+16 for w_hh)] x K=1024, loaded ONCE;
// plus one 64b x 64k activation chunk, re-staged per chunk with issue-early loads.
// Thread (b = tid>>3, j4 = (tid>>1)&3, gp = tid&1) accumulates gates {2gp, 2gp+1}.
__global__ __launch_bounds__(NTHR, 2)
void skiplstm(const float* __restrict__ x,
              const float* __restrict__ h0,
              const float* __restrict__ c0,
              const float* __restrict__ w_ih,
              const float* __restrict__ w_hh,
              const float* __restrict__ b_ih,
              const float* __restrict__ b_hh,
              const int* __restrict__ bias_flag,
              float* __restrict__ out)   // [T][B][H] then h_final, c_final
{
    extern __shared__ float lds[];
    float* wl = lds;                 // [32][WSTR]
    float* al = lds + W_FLOATS;      // [64][ASTR]

    cg::grid_group grid = cg::this_grid();

    const int tid = threadIdx.x;
    const int b   = tid >> 3;        // 0..63
    const int j4  = (tid >> 1) & 3;  // 0..3
    const int gp  = tid & 1;         // gate pair: {i,f} or {g,o}
    const int jb  = blockIdx.x * JPB;
    const int j   = jb + j4;
    const int gA  = gp * 2, gB = gp * 2 + 1;

    // ---- one-time: stage this block's 32 weight rows into LDS (128 KB) ----
    for (int idx = tid; idx < 32 * 256; idx += NTHR) {
        const int row = idx >> 8;          // 0..31
        const int k4  = idx & 255;         // float4 index in row
        const int rr  = row & 15;          // jj = rr>>2, gate = rr&3
        const float* srcw = (row < 16 ? w_ih : w_hh)
                          + (size_t)((rr & 3) * NH + jb + (rr >> 2)) * NI;
        *(float4*)(wl + (size_t)row * WSTR + k4 * 4) =
            *(const float4*)(srcw + k4 * 4);
    }
    __syncthreads();

    const float bsc = (bias_flag[0] != 0) ? 1.0f : 0.0f;
    const float bA = (b_ih[gA * NH + j] + b_hh[gA * NH + j]) * bsc;
    const float bB = (b_ih[gB * NH + j] + b_hh[gB * NH + j]) * bsc;

    float c = c0[(size_t)b * NH + j];      // meaningful on gp==0 lanes
    float q0 = 0.f, q1 = 0.f, q2 = 0.f, q3 = 0.f;  // skip ring (gp==0)

    const int   rst = tid >> 3;            // act row this thread stages (== b)
    const int   cst = (tid & 7) * 8;       // 8 floats within the 64-float chunk

    float aA, aB;
    // One K-chunked GEMM pass: acts staged to LDS with issue-early/write-late.
    auto mmloop = [&](const float* __restrict__ src, int wbase) {
        const float* wrA = wl + (size_t)(wbase + j4 * 4 + gA) * WSTR;
        const float* wrB = wl + (size_t)(wbase + j4 * 4 + gB) * WSTR;
        const float* ab  = al + b * ASTR;
        const float* my  = src + (size_t)rst * 1024 + cst;
        // prologue: chunk 0
        float4 r0 = *(const float4*)(my);
        float4 r1 = *(const float4*)(my + 4);
        *(float4*)(al + rst * ASTR + cst)     = r0;
        *(float4*)(al + rst * ASTR + cst + 4) = r1;
        __syncthreads();
        for (int ch = 0; ch < NCH; ++ch) {
            float4 n0, n1;
            if (ch + 1 < NCH) {              // issue next chunk early (T14)
                n0 = *(const float4*)(my + (ch + 1) * CK);
                n1 = *(const float4*)(my + (ch + 1) * CK + 4);
            }
            const int kb = ch * CK;
            #pragma unroll
            for (int kk = 0; kk < CK / 4; ++kk) {
                float4 av = *(const float4*)(ab + kk * 4);
                float4 wa = *(const float4*)(wrA + kb + kk * 4);
                float4 wv = *(const float4*)(wrB + kb + kk * 4);
                aA += dot4(av, wa);
                aB += dot4(av, wv);
            }
            __syncthreads();                 // all done reading chunk ch
            if (ch + 1 < NCH) {
                *(float4*)(al + rst * ASTR + cst)     = n0;
                *(float4*)(al + rst * ASTR + cst + 4) = n1;
                __syncthreads();             // chunk ch+1 visible
            }
        }
    };

    for (int t = 0; t < NT; ++t) {
        aA = bA; aB = bB;

        // ---- x_t @ w_ih^T (independent of recurrence; pre-barrier) ----
        mmloop(x + (size_t)t * NB * NI, 0);

        // make every block's out[t-1] writes visible before h staging
        grid.sync();

        // ---- h_{t-1} @ w_hh^T ; h_{t-1} lives in out[t-1] (post-skip h) ----
        mmloop((t == 0) ? h0 : (out + (size_t)(t - 1) * BH), 16);

        // ---- pair exchange + gates (meaningful on gp==0 lanes) ----
        float pG = __shfl_xor(aA, 1);
        float pO = __shfl_xor(aB, 1);
        float ig = sigm(aA);
        float fg = sigm(aB);
        float gv = tanhf(pG);
        float og = sigm(pO);
        c = fg * c + ig * gv;
        float hn = og * tanhf(c);
        float ho = hn + ((t >= 4) ? q3 : 0.0f);   // skip: own out[t-4]
        q3 = q2; q2 = q1; q1 = q0; q0 = ho;
        if (gp == 0)
            out[(size_t)t * BH + (size_t)b * NH + j] = ho;
    }

    // Tuple tail: h_final = out[T-1], c_final.
    if (gp == 0) {
        out[TBH + (size_t)b * NH + j] = q0;
        out[TBH + BH + (size_t)b * NH + j] = c;
    }
}

extern "C" void kernel_launch(void* const* d_in, const int* in_sizes, int n_in,
                              void* d_out, int out_size, void* d_ws, size_t ws_size,
                              hipStream_t stream) {
    const float* x    = (const float*)d_in[0];
    const float* h0   = (const float*)d_in[1];
    const float* c0   = (const float*)d_in[2];
    const float* w_ih = (const float*)d_in[3];
    const float* w_hh = (const float*)d_in[4];
    const float* b_ih = (const float*)d_in[5];
    const float* b_hh = (const float*)d_in[6];
    const int* bias   = (const int*)d_in[7];
    float* out        = (float*)d_out;

    // 149 KB dynamic LDS > 64 KB default cap — raise the attribute (idempotent,
    // host-side, not a stream op: graph-capture-safe).
    hipFuncSetAttribute((const void*)skiplstm,
                        hipFuncAttributeMaxDynamicSharedMemorySize,
                        (int)LDS_BYTES);

    void* args[] = {(void*)&x, (void*)&h0, (void*)&c0, (void*)&w_ih, (void*)&w_hh,
                    (void*)&b_ih, (void*)&b_hh, (void*)&bias, (void*)&out};
    hipLaunchCooperativeKernel((void*)skiplstm, dim3(NBLK), dim3(NTHR), args,
                               (uint32_t)LDS_BYTES, stream);
}

// Round 7
// 20806.137 us; speedup vs baseline: 7.1827x; 1.4046x over previous
//
#include <hip/hip_runtime.h>
#include <hip/hip_cooperative_groups.h>

namespace cg = cooperative_groups;

constexpr int NT = 512, NB = 64, NH = 1024, NI = 1024;
constexpr long long BH  = (long long)NB * NH;   // 65536
constexpr long long TBH = (long long)NT * BH;

constexpr int NTHR = 512;            // 8 waves: bt = w&3 (16-row b-tile), kh = w>>2 (K half)
constexpr int NBLK = 256;            // 256 col-groups: 4 j-cols x 4 gates = 16 N-cols, full batch
constexpr float LOSC  = 4096.0f;     // lo-plane scale (keeps residuals f16-normal)
constexpr float LOSCI = 1.0f / 4096.0f;
constexpr size_t WBYTES = 131072;    // 2 mat x 32 slices x 2 planes x 512 f16 x 2 B
constexpr size_t LDSB   = WBYTES + 8192;  // + reduce buffer (4 waves x 64 x 8 f32)

using f16   = _Float16;
using f16x8 = __attribute__((ext_vector_type(8))) f16;
using f32x4 = __attribute__((ext_vector_type(4))) float;

// Split-f16 MFMA skip-LSTM. Weights resident in LDS as hi/lo f16 fragment planes
// (lo pre-scaled x4096). A (x_t / h_{t-1}) read from global fp32, split in-register.
// z = accM + accC/4096 with accM = sum Ah*Bh, accC = sum (Ah*Bl' + Al'*Bh).
// B-frag lane map == A-frag lane map (k = s*32 + (l>>4)*8 + e) -> any hw k-permutation
// cancels between A and B. C/D: col = l&15 (N), row = (l>>4)*4 + reg (M) [m89-verified].
__global__ __launch_bounds__(NTHR, 2)
void skiplstm(const float* __restrict__ x,
              const float* __restrict__ h0,
              const float* __restrict__ c0,
              const float* __restrict__ w_ih,
              const float* __restrict__ w_hh,
              const float* __restrict__ b_ih,
              const float* __restrict__ b_hh,
              const int* __restrict__ bias_flag,
              float* __restrict__ out)   // [T][B][H] then h_final, c_final
{
    extern __shared__ char lds[];
    f16*   wl  = (f16*)lds;              // 65536 f16: frag(m,sg,p) = ((m*32+sg)*2+p)*512 + l*8
    float* red = (float*)(lds + WBYTES); // 2048 f32 reduce

    cg::grid_group grid = cg::this_grid();

    const int tid = threadIdx.x;
    const int l   = tid & 63;
    const int w   = tid >> 6;
    const int bt  = w & 3;           // batch tile of 16
    const int kh  = w >> 2;          // K half (512 per matrix)
    const int n   = l & 15;          // N col within tile / A row within b-tile
    const int kg  = l >> 4;          // k-group
    const int cgi = blockIdx.x;      // col-group: j = cgi*4 .. +3

    // ---- one-time: weights -> hi/lo f16 LDS planes ----
    for (int idx = tid; idx < 32768; idx += NTHR) {
        const int e  = idx & 7;
        const int ll = (idx >> 3) & 63;
        const int sg = (idx >> 9) & 31;
        const int m  = (idx >> 14) & 1;
        const int cc = ll & 15;                       // col: jo = cc>>2, gate = cc&3
        const int k  = sg * 32 + (ll >> 4) * 8 + e;
        const float* W = m ? w_hh : w_ih;
        const float v = W[(size_t)((cc & 3) * NH + cgi * 4 + (cc >> 2)) * NI + k];
        const f16 vh = (f16)v;
        const f16 vl = (f16)((v - (float)vh) * LOSC);
        const size_t base = (size_t)(m * 32 + sg) * 1024 + ll * 8 + e;
        wl[base]       = vh;                          // p=0 (hi) plane
        wl[base + 512] = vl;                          // p=1 (lo*4096) plane
    }
    __syncthreads();

    // per-lane column bias: col n -> W row (n&3)*NH + cgi*4 + (n>>2)
    const float bsc = (bias_flag[0] != 0) ? 1.0f : 0.0f;
    const int   jme = cgi * 4 + (n >> 2);
    const float bC  = (b_ih[(n & 3) * NH + jme] + b_hh[(n & 3) * NH + jme]) * bsc;

    // cell state + 4-deep skip ring (meaningful on waves 0..3, owner lanes n%4==0)
    float cst[4], ring[4][4];
    #pragma unroll
    for (int r = 0; r < 4; ++r) {
        const int b = bt * 16 + kg * 4 + r;
        cst[r] = c0[(size_t)b * NH + jme];
        #pragma unroll
        for (int q = 0; q < 4; ++q) ring[r][q] = 0.0f;
    }

    const int arow = bt * 16 + n;    // this lane's activation row (batch)

    f32x4 accM, accC;
    // one matrix phase: 16 slices of this wave's K half, 3 MFMAs each
    auto phase = [&](const float* __restrict__ Ar, int m) {
        #pragma unroll
        for (int s8 = 0; s8 < 16; ++s8) {
            const int sg = kh * 16 + s8;
            const float* p = Ar + sg * 32 + kg * 8;
            f32x4 vlo = *(const f32x4*)p;
            f32x4 vhi = *(const f32x4*)(p + 4);
            f16x8 ah, al;
            #pragma unroll
            for (int e2 = 0; e2 < 4; ++e2) {
                const float v0 = vlo[e2], v1 = vhi[e2];
                ah[e2]     = (f16)v0;
                al[e2]     = (f16)((v0 - (float)ah[e2]) * LOSC);
                ah[e2 + 4] = (f16)v1;
                al[e2 + 4] = (f16)((v1 - (float)ah[e2 + 4]) * LOSC);
            }
            const f16* fb = wl + (size_t)(m * 32 + sg) * 1024 + l * 8;
            f16x8 bh_ = *(const f16x8*)fb;
            f16x8 bl_ = *(const f16x8*)(fb + 512);
            accM = __builtin_amdgcn_mfma_f32_16x16x32_f16(ah, bh_, accM, 0, 0, 0);
            accC = __builtin_amdgcn_mfma_f32_16x16x32_f16(ah, bl_, accC, 0, 0, 0);
            accC = __builtin_amdgcn_mfma_f32_16x16x32_f16(al, bh_, accC, 0, 0, 0);
        }
    };

    for (int t = 0; t < NT; ++t) {
        accM = f32x4{0.f, 0.f, 0.f, 0.f};
        accC = f32x4{0.f, 0.f, 0.f, 0.f};

        // ---- x-part (independent of recurrence; pre-barrier) ----
        phase(x + ((size_t)t * NB + arow) * NI, 0);

        grid.sync();   // all blocks' out[t-1] writes visible

        // ---- h-part: h_{t-1} = out[t-1] (post-skip) ----
        const float* hsrc = (t == 0) ? h0 : (out + (size_t)(t - 1) * BH);
        phase(hsrc + (size_t)arow * NH, 1);

        // ---- cross-wave K-reduce: waves 4..7 (kh=1) hand partials to 0..3 ----
        if (w >= 4) {
            float* rp = red + ((size_t)(w - 4) * 64 + l) * 8;
            *(f32x4*)rp       = accM;
            *(f32x4*)(rp + 4) = accC;
        }
        __syncthreads();
        // red reuse at t+1 happens after grid.sync(t+1) -> no second barrier.

        if (w < 4) {
            const float* rp = red + ((size_t)w * 64 + l) * 8;
            accM += *(const f32x4*)rp;
            accC += *(const f32x4*)(rp + 4);

            // gates: quad lanes n^{0,1,2,3} hold i,f,g,o for (j = jme, b row)
            #pragma unroll
            for (int r = 0; r < 4; ++r) {
                const float v  = accM[r] + accC[r] * LOSCI + bC;
                const float zf = __shfl_xor(v, 1);
                const float zg = __shfl_xor(v, 2);
                const float zo = __shfl_xor(v, 3);
                const float ig = 1.0f / (1.0f + expf(-v));
                const float fg = 1.0f / (1.0f + expf(-zf));
                const float gv = tanhf(zg);
                const float og = 1.0f / (1.0f + expf(-zo));
                const float cn = fg * cst[r] + ig * gv;
                cst[r] = cn;
                const float hn = og * tanhf(cn);
                const float ho = hn + ((t >= 4) ? ring[r][3] : 0.0f);  // + h_out[t-4]
                ring[r][3] = ring[r][2];
                ring[r][2] = ring[r][1];
                ring[r][1] = ring[r][0];
                ring[r][0] = ho;
                if ((n & 3) == 0) {
                    const int b = bt * 16 + kg * 4 + r;
                    out[(size_t)t * BH + (size_t)b * NH + jme] = ho;
                }
            }
        }
    }

    // ---- tuple tail: h_final = out[T-1], c_final ----
    if (w < 4 && (n & 3) == 0) {
        #pragma unroll
        for (int r = 0; r < 4; ++r) {
            const int b = bt * 16 + kg * 4 + r;
            out[TBH + (size_t)b * NH + jme] = ring[r][0];
            out[TBH + BH + (size_t)b * NH + jme] = cst[r];
        }
    }
}

extern "C" void kernel_launch(void* const* d_in, const int* in_sizes, int n_in,
                              void* d_out, int out_size, void* d_ws, size_t ws_size,
                              hipStream_t stream) {
    const float* x    = (const float*)d_in[0];
    const float* h0   = (const float*)d_in[1];
    const float* c0   = (const float*)d_in[2];
    const float* w_ih = (const float*)d_in[3];
    const float* w_hh = (const float*)d_in[4];
    const float* b_ih = (const float*)d_in[5];
    const float* b_hh = (const float*)d_in[6];
    const int* bias   = (const int*)d_in[7];
    float* out        = (float*)d_out;
    (void)d_ws; (void)ws_size;

    // 136 KB dynamic LDS > 64 KB default cap (host-side attr, graph-capture-safe).
    hipFuncSetAttribute((const void*)skiplstm,
                        hipFuncAttributeMaxDynamicSharedMemorySize, (int)LDSB);

    void* args[] = {(void*)&x, (void*)&h0, (void*)&c0, (void*)&w_ih, (void*)&w_hh,
                    (void*)&b_ih, (void*)&b_hh, (void*)&bias, (void*)&out};
    hipLaunchCooperativeKernel((void*)skiplstm, dim3(NBLK), dim3(NTHR), args,
                               (uint32_t)LDSB, stream);
}